// Round 1
// baseline (222.964 us; speedup 1.0000x reference)
//
#include <hip/hip_runtime.h>

// Problem: B=256 samples, D=2048 dims, N=16384 memory-bank rows.
// loss = hard-sample NLL over (psid,cam) groups; dominant cost is
// sims = normalize(inputs) @ features^T / 0.05 reduced to per-row logsumexp.

constexpr int Bn = 256;     // batch
constexpr int Dk = 2048;    // feature dim
constexpr int Nn = 16384;   // bank rows
constexpr int BN = 64;      // N-cols per block
constexpr int BK = 64;      // K-chunk
constexpr int NK = Dk / BK; // 32
constexpr float TEMP_INV = 20.0f;

typedef float f32x4 __attribute__((ext_vector_type(4)));
typedef short s16x8 __attribute__((ext_vector_type(8)));
typedef unsigned int u32x4 __attribute__((ext_vector_type(4)));

__device__ inline unsigned short f2bf(float f) {
  union { float f; unsigned u; } v; v.f = f;
  unsigned r = v.u + 0x7FFFu + ((v.u >> 16) & 1u);   // RNE
  return (unsigned short)(r >> 16);
}

// ---------------- kernel 1: row-normalize inputs -> bf16, store inv_norm ----
__global__ __launch_bounds__(256) void norm_kernel(
    const float* __restrict__ x, unsigned short* __restrict__ xb,
    float* __restrict__ inv_norm) {
  int row = blockIdx.x, t = threadIdx.x;
  const float* xr = x + (size_t)row * Dk;
  float4 a = *(const float4*)(xr + t * 8);
  float4 b = *(const float4*)(xr + t * 8 + 4);
  float ss = a.x*a.x + a.y*a.y + a.z*a.z + a.w*a.w
           + b.x*b.x + b.y*b.y + b.z*b.z + b.w*b.w;
  #pragma unroll
  for (int d = 1; d < 64; d <<= 1) ss += __shfl_xor(ss, d, 64);
  __shared__ float red[4];
  if ((t & 63) == 0) red[t >> 6] = ss;
  __syncthreads();
  float inv = rsqrtf(red[0] + red[1] + red[2] + red[3]);
  union { unsigned short s[8]; uint4 v; } pk;
  pk.s[0] = f2bf(a.x*inv); pk.s[1] = f2bf(a.y*inv);
  pk.s[2] = f2bf(a.z*inv); pk.s[3] = f2bf(a.w*inv);
  pk.s[4] = f2bf(b.x*inv); pk.s[5] = f2bf(b.y*inv);
  pk.s[6] = f2bf(b.z*inv); pk.s[7] = f2bf(b.w*inv);
  *(uint4*)(xb + (size_t)row * Dk + t * 8) = pk.v;
  if (t == 0) inv_norm[row] = inv;
}

// ---------------- kernel 2: s_own[i] = dot(x_i, feat[t_i]) * inv_norm / TEMP (f32 exact) ----
__global__ __launch_bounds__(256) void sown_kernel(
    const float* __restrict__ x, const float* __restrict__ feats,
    const int* __restrict__ targets, const float* __restrict__ inv_norm,
    float* __restrict__ s_own) {
  int i = blockIdx.x, t = threadIdx.x;
  const float* xr = x + (size_t)i * Dk;
  const float* fr = feats + (size_t)targets[i] * Dk;
  float4 a  = *(const float4*)(xr + t * 8);
  float4 b  = *(const float4*)(xr + t * 8 + 4);
  float4 fa = *(const float4*)(fr + t * 8);
  float4 fb = *(const float4*)(fr + t * 8 + 4);
  float s = a.x*fa.x + a.y*fa.y + a.z*fa.z + a.w*fa.w
          + b.x*fb.x + b.y*fb.y + b.z*fb.z + b.w*fb.w;
  #pragma unroll
  for (int d = 1; d < 64; d <<= 1) s += __shfl_xor(s, d, 64);
  __shared__ float red[4];
  if ((t & 63) == 0) red[t >> 6] = s;
  __syncthreads();
  if (t == 0) s_own[i] = (red[0] + red[1] + red[2] + red[3]) * inv_norm[i] * TEMP_INV;
}

// ---------------- kernel 3: fused GEMM + per-row partial max/sumexp ---------
// grid = N/BN = 256 blocks, 512 threads (8 waves: wm=w>>1 in [0,4), wn=w&1).
// Each block: all 256 rows x 64 feature cols. A (x bf16) via global_load_lds
// (linear LDS dest, pre-swizzled SOURCE); B (features f32) reg-staged with
// cvt + swizzled ds_write. XOR swizzle: 16B granule g at row r -> g^(r&7).
__global__ __launch_bounds__(512) void gemm_kernel(
    const unsigned short* __restrict__ xb, const float* __restrict__ feats,
    float* __restrict__ pmax, float* __restrict__ psum) {
  __shared__ unsigned char As[256 * 128]; // [256 rows][8 granules*16B] = 32KB
  __shared__ unsigned char Bs[64 * 128];  // 8KB

  int tid = threadIdx.x;
  int w = tid >> 6, lane = tid & 63;
  int wm = w >> 1, wn = w & 1;
  int nb = blockIdx.x, n0 = nb * BN;

  f32x4 acc[4][2];
  #pragma unroll
  for (int mt = 0; mt < 4; ++mt)
    #pragma unroll
    for (int nt = 0; nt < 2; ++nt)
      acc[mt][nt] = (f32x4){0.f, 0.f, 0.f, 0.f};

  // B staging geometry: thread t handles feature row br, 8-float granule bg
  int br = tid >> 3, bg = tid & 7;
  const float* fptr = feats + (size_t)(n0 + br) * Dk + bg * 8;
  unsigned char* bdst = Bs + br * 128 + ((bg ^ (br & 7)) << 4);

  // prefetch B regs for kt=0
  float4 f0 = *(const float4*)(fptr);
  float4 f1 = *(const float4*)(fptr + 4);

  for (int kt = 0; kt < NK; ++kt) {
    int k0 = kt * BK;
    __syncthreads(); // previous compute done; LDS free
    // A: 4 x global_load_lds(16B) per thread; dest wave-uniform + lane*16
    #pragma unroll
    for (int j = 0; j < 4; ++j) {
      int G = (w * 4 + j) * 64 + lane;
      int r = G >> 3, g = G & 7;
      const unsigned short* src = xb + (size_t)r * Dk + k0 + ((g ^ (r & 7)) << 3);
      __builtin_amdgcn_global_load_lds(
          (const __attribute__((address_space(1))) unsigned int*)src,
          (__attribute__((address_space(3))) unsigned int*)(As + (w * 4 + j) * 1024),
          16, 0, 0);
    }
    // B: cvt regs -> bf16, swizzled ds_write_b128
    {
      union { unsigned short s[8]; u32x4 v; } pk;
      pk.s[0] = f2bf(f0.x); pk.s[1] = f2bf(f0.y); pk.s[2] = f2bf(f0.z); pk.s[3] = f2bf(f0.w);
      pk.s[4] = f2bf(f1.x); pk.s[5] = f2bf(f1.y); pk.s[6] = f2bf(f1.z); pk.s[7] = f2bf(f1.w);
      *(u32x4*)bdst = pk.v;
    }
    __syncthreads(); // A landed + B written
    // prefetch next-iter B regs: latency hides under the MFMA phase
    if (kt + 1 < NK) {
      f0 = *(const float4*)(fptr + k0 + BK);
      f1 = *(const float4*)(fptr + k0 + BK + 4);
    }
    #pragma unroll
    for (int ks = 0; ks < 2; ++ks) {
      int g = ks * 4 + (lane >> 4);
      s16x8 bfr[2];
      #pragma unroll
      for (int nt = 0; nt < 2; ++nt) {
        int n = wn * 32 + nt * 16 + (lane & 15);
        bfr[nt] = *(const s16x8*)(Bs + n * 128 + ((g ^ (n & 7)) << 4));
      }
      #pragma unroll
      for (int mt = 0; mt < 4; ++mt) {
        int r = wm * 64 + mt * 16 + (lane & 15);
        s16x8 af = *(const s16x8*)(As + r * 128 + ((g ^ (r & 7)) << 4));
        acc[mt][0] = __builtin_amdgcn_mfma_f32_16x16x32_bf16(af, bfr[0], acc[mt][0], 0, 0, 0);
        acc[mt][1] = __builtin_amdgcn_mfma_f32_16x16x32_bf16(af, bfr[1], acc[mt][1], 0, 0, 0);
      }
    }
  }

  // epilogue: per-row partial max / sumexp over this wave's 32 cols.
  // C/D layout: col = lane&15, row = (lane>>4)*4 + reg  (guide §3, m89-verified)
  int pb = nb * 2 + wn; // 512 partial column-chunks
  #pragma unroll
  for (int mt = 0; mt < 4; ++mt) {
    #pragma unroll
    for (int rg = 0; rg < 4; ++rg) {
      float v0 = acc[mt][0][rg] * TEMP_INV;
      float v1 = acc[mt][1][rg] * TEMP_INV;
      float m = fmaxf(v0, v1);
      #pragma unroll
      for (int d = 1; d < 16; d <<= 1) m = fmaxf(m, __shfl_xor(m, d, 64));
      float s = __expf(v0 - m) + __expf(v1 - m);
      #pragma unroll
      for (int d = 1; d < 16; d <<= 1) s += __shfl_xor(s, d, 64);
      if ((lane & 15) == 0) {
        int row = wm * 64 + mt * 16 + (lane >> 4) * 4 + rg;
        pmax[pb * 256 + row] = m;
        psum[pb * 256 + row] = s;
      }
    }
  }
}

// ---------------- kernel 4: combine partials + group logic -> loss ----------
__global__ __launch_bounds__(256) void finish_kernel(
    const float* __restrict__ pmax, const float* __restrict__ psum,
    const float* __restrict__ s_own, const int* __restrict__ targets,
    const int* __restrict__ cams, float* __restrict__ out) {
  int i = threadIdx.x;
  float m = -1e30f;
  for (int pb = 0; pb < 512; ++pb) m = fmaxf(m, pmax[pb * 256 + i]);
  float s = 0.f;
  for (int pb = 0; pb < 512; ++pb) s += psum[pb * 256 + i] * __expf(pmax[pb * 256 + i] - m);
  float lse = m + logf(s);

  __shared__ float so[256]; __shared__ int tg[256], cmn[256];
  __shared__ float gfirst[256];
  so[i] = s_own[i]; tg[i] = targets[i]; cmn[i] = cams[i];
  __syncthreads();
  int ti = tg[i], ci = cmn[i]; float soi = so[i];
  float gmin = 1e30f;
  bool grp_first = true, psid_first = true;
  for (int j = 0; j < 256; ++j) {
    if (tg[j] == ti) {
      if (j < i) psid_first = false;
      if (cmn[j] == ci) {
        gmin = fminf(gmin, so[j]);
        if (j < i) grp_first = false;
      }
    }
  }
  bool ismin = (soi <= gmin);
  gfirst[i] = grp_first ? 1.f : 0.f;
  __syncthreads();
  float ngroups = 0.f; bool prior = false;
  for (int j = 0; j < 256; ++j) {
    if (tg[j] == ti) {
      ngroups += gfirst[j];
      if (j < i && cmn[j] == ci && so[j] <= gmin) prior = true; // is_min[j], same gmin per group
    }
  }
  float contrib = (ismin && !prior) ? (lse - soi) / ngroups : 0.f;
  float pf = psid_first ? 1.f : 0.f;
  #pragma unroll
  for (int d = 1; d < 64; d <<= 1) {
    contrib += __shfl_xor(contrib, d, 64);
    pf += __shfl_xor(pf, d, 64);
  }
  __shared__ float rc[4], rp[4];
  if ((i & 63) == 0) { rc[i >> 6] = contrib; rp[i >> 6] = pf; }
  __syncthreads();
  if (i == 0) out[0] = (rc[0] + rc[1] + rc[2] + rc[3]) / (rp[0] + rp[1] + rp[2] + rp[3]);
}

extern "C" void kernel_launch(void* const* d_in, const int* in_sizes, int n_in,
                              void* d_out, int out_size, void* d_ws, size_t ws_size,
                              hipStream_t stream) {
  const float* inputs  = (const float*)d_in[0];
  const float* feats   = (const float*)d_in[1];
  const int*   targets = (const int*)d_in[2];
  const int*   cams    = (const int*)d_in[3];
  float* out = (float*)d_out;
  char* ws = (char*)d_ws;
  // ws layout (all 16B-aligned): inv_norm 1KB | s_own 1KB | pad | pmax 512KB | psum 512KB | x_bf16 1MB
  float* inv_norm = (float*)(ws);
  float* s_own    = (float*)(ws + 1024);
  float* pmax     = (float*)(ws + 4096);
  float* psum     = (float*)(ws + 4096 + 512 * 1024);
  unsigned short* xb = (unsigned short*)(ws + 4096 + 1024 * 1024);

  norm_kernel<<<Bn, 256, 0, stream>>>(inputs, xb, inv_norm);
  sown_kernel<<<Bn, 256, 0, stream>>>(inputs, feats, targets, inv_norm, s_own);
  gemm_kernel<<<Nn / BN, 512, 0, stream>>>(xb, feats, pmax, psum);
  finish_kernel<<<1, 256, 0, stream>>>(pmax, psum, s_own, targets, cams, out);
}

// Round 2
// 119.827 us; speedup vs baseline: 1.8607x; 1.8607x over previous
//
#include <hip/hip_runtime.h>

// Problem: B=256 samples, D=2048 dims, N=16384 memory-bank rows.
// loss = hard-sample NLL over (psid,cam) groups; dominant cost is
// sims = normalize(inputs) @ features^T / 0.05 reduced to per-row logsumexp.

constexpr int Bn = 256;     // batch
constexpr int Dk = 2048;    // feature dim
constexpr int Nn = 16384;   // bank rows
constexpr int BN = 64;      // N-cols per block
constexpr int BK = 64;      // K-chunk
constexpr int NK = Dk / BK; // 32
constexpr int NPB = 512;    // partial chunks (Nn/BN * 2)
constexpr float TEMP_INV = 20.0f;

typedef float f32x4 __attribute__((ext_vector_type(4)));
typedef short s16x8 __attribute__((ext_vector_type(8)));
typedef unsigned int u32x4 __attribute__((ext_vector_type(4)));

__device__ inline unsigned short f2bf(float f) {
  union { float f; unsigned u; } v; v.f = f;
  unsigned r = v.u + 0x7FFFu + ((v.u >> 16) & 1u);   // RNE
  return (unsigned short)(r >> 16);
}

// ---------------- kernel 1: row-normalize inputs -> bf16, store inv_norm ----
__global__ __launch_bounds__(256) void norm_kernel(
    const float* __restrict__ x, unsigned short* __restrict__ xb,
    float* __restrict__ inv_norm) {
  int row = blockIdx.x, t = threadIdx.x;
  const float* xr = x + (size_t)row * Dk;
  float4 a = *(const float4*)(xr + t * 8);
  float4 b = *(const float4*)(xr + t * 8 + 4);
  float ss = a.x*a.x + a.y*a.y + a.z*a.z + a.w*a.w
           + b.x*b.x + b.y*b.y + b.z*b.z + b.w*b.w;
  #pragma unroll
  for (int d = 1; d < 64; d <<= 1) ss += __shfl_xor(ss, d, 64);
  __shared__ float red[4];
  if ((t & 63) == 0) red[t >> 6] = ss;
  __syncthreads();
  float inv = rsqrtf(red[0] + red[1] + red[2] + red[3]);
  union { unsigned short s[8]; uint4 v; } pk;
  pk.s[0] = f2bf(a.x*inv); pk.s[1] = f2bf(a.y*inv);
  pk.s[2] = f2bf(a.z*inv); pk.s[3] = f2bf(a.w*inv);
  pk.s[4] = f2bf(b.x*inv); pk.s[5] = f2bf(b.y*inv);
  pk.s[6] = f2bf(b.z*inv); pk.s[7] = f2bf(b.w*inv);
  *(uint4*)(xb + (size_t)row * Dk + t * 8) = pk.v;
  if (t == 0) inv_norm[row] = inv;
}

// ---------------- kernel 2: s_own[i] = dot(x_i, feat[t_i]) * inv_norm / TEMP (f32 exact) ----
__global__ __launch_bounds__(256) void sown_kernel(
    const float* __restrict__ x, const float* __restrict__ feats,
    const int* __restrict__ targets, const float* __restrict__ inv_norm,
    float* __restrict__ s_own) {
  int i = blockIdx.x, t = threadIdx.x;
  const float* xr = x + (size_t)i * Dk;
  const float* fr = feats + (size_t)targets[i] * Dk;
  float4 a  = *(const float4*)(xr + t * 8);
  float4 b  = *(const float4*)(xr + t * 8 + 4);
  float4 fa = *(const float4*)(fr + t * 8);
  float4 fb = *(const float4*)(fr + t * 8 + 4);
  float s = a.x*fa.x + a.y*fa.y + a.z*fa.z + a.w*fa.w
          + b.x*fb.x + b.y*fb.y + b.z*fb.z + b.w*fb.w;
  #pragma unroll
  for (int d = 1; d < 64; d <<= 1) s += __shfl_xor(s, d, 64);
  __shared__ float red[4];
  if ((t & 63) == 0) red[t >> 6] = s;
  __syncthreads();
  if (t == 0) s_own[i] = (red[0] + red[1] + red[2] + red[3]) * inv_norm[i] * TEMP_INV;
}

// ---------------- kernel 3: fused GEMM + per-row partial max/sumexp ---------
// grid = N/BN = 256 blocks, 512 threads (8 waves: wm=w>>1 in [0,4), wn=w&1).
// Each block: all 256 rows x 64 feature cols. A (x bf16) via global_load_lds
// (linear LDS dest, pre-swizzled SOURCE); B (features f32) reg-staged with
// cvt + swizzled ds_write. XOR swizzle: 16B granule g at row r -> g^(r&7).
__global__ __launch_bounds__(512) void gemm_kernel(
    const unsigned short* __restrict__ xb, const float* __restrict__ feats,
    float* __restrict__ pmax, float* __restrict__ psum) {
  __shared__ unsigned char As[256 * 128]; // [256 rows][8 granules*16B] = 32KB
  __shared__ unsigned char Bs[64 * 128];  // 8KB

  int tid = threadIdx.x;
  int w = tid >> 6, lane = tid & 63;
  int wm = w >> 1, wn = w & 1;
  int nb = blockIdx.x, n0 = nb * BN;

  f32x4 acc[4][2];
  #pragma unroll
  for (int mt = 0; mt < 4; ++mt)
    #pragma unroll
    for (int nt = 0; nt < 2; ++nt)
      acc[mt][nt] = (f32x4){0.f, 0.f, 0.f, 0.f};

  // B staging geometry: thread t handles feature row br, 8-float granule bg
  int br = tid >> 3, bg = tid & 7;
  const float* fptr = feats + (size_t)(n0 + br) * Dk + bg * 8;
  unsigned char* bdst = Bs + br * 128 + ((bg ^ (br & 7)) << 4);

  // prefetch B regs for kt=0
  float4 f0 = *(const float4*)(fptr);
  float4 f1 = *(const float4*)(fptr + 4);

  for (int kt = 0; kt < NK; ++kt) {
    int k0 = kt * BK;
    __syncthreads(); // previous compute done; LDS free
    // A: 4 x global_load_lds(16B) per thread; dest wave-uniform + lane*16
    #pragma unroll
    for (int j = 0; j < 4; ++j) {
      int G = (w * 4 + j) * 64 + lane;
      int r = G >> 3, g = G & 7;
      const unsigned short* src = xb + (size_t)r * Dk + k0 + ((g ^ (r & 7)) << 3);
      __builtin_amdgcn_global_load_lds(
          (const __attribute__((address_space(1))) unsigned int*)src,
          (__attribute__((address_space(3))) unsigned int*)(As + (w * 4 + j) * 1024),
          16, 0, 0);
    }
    // B: cvt regs -> bf16, swizzled ds_write_b128
    {
      union { unsigned short s[8]; u32x4 v; } pk;
      pk.s[0] = f2bf(f0.x); pk.s[1] = f2bf(f0.y); pk.s[2] = f2bf(f0.z); pk.s[3] = f2bf(f0.w);
      pk.s[4] = f2bf(f1.x); pk.s[5] = f2bf(f1.y); pk.s[6] = f2bf(f1.z); pk.s[7] = f2bf(f1.w);
      *(u32x4*)bdst = pk.v;
    }
    __syncthreads(); // A landed + B written
    // prefetch next-iter B regs: latency hides under the MFMA phase
    if (kt + 1 < NK) {
      f0 = *(const float4*)(fptr + k0 + BK);
      f1 = *(const float4*)(fptr + k0 + BK + 4);
    }
    #pragma unroll
    for (int ks = 0; ks < 2; ++ks) {
      int g = ks * 4 + (lane >> 4);
      s16x8 bfr[2];
      #pragma unroll
      for (int nt = 0; nt < 2; ++nt) {
        int n = wn * 32 + nt * 16 + (lane & 15);
        bfr[nt] = *(const s16x8*)(Bs + n * 128 + ((g ^ (n & 7)) << 4));
      }
      #pragma unroll
      for (int mt = 0; mt < 4; ++mt) {
        int r = wm * 64 + mt * 16 + (lane & 15);
        s16x8 af = *(const s16x8*)(As + r * 128 + ((g ^ (r & 7)) << 4));
        acc[mt][0] = __builtin_amdgcn_mfma_f32_16x16x32_bf16(af, bfr[0], acc[mt][0], 0, 0, 0);
        acc[mt][1] = __builtin_amdgcn_mfma_f32_16x16x32_bf16(af, bfr[1], acc[mt][1], 0, 0, 0);
      }
    }
  }

  // epilogue: per-row partial max / sumexp over this wave's 32 cols.
  // C/D layout: col = lane&15, row = (lane>>4)*4 + reg  (guide §3, m89-verified)
  // Partials stored TRANSPOSED: pmax[row * NPB + pb] for coalesced combine.
  int pb = nb * 2 + wn; // 512 partial column-chunks
  #pragma unroll
  for (int mt = 0; mt < 4; ++mt) {
    #pragma unroll
    for (int rg = 0; rg < 4; ++rg) {
      float v0 = acc[mt][0][rg] * TEMP_INV;
      float v1 = acc[mt][1][rg] * TEMP_INV;
      float m = fmaxf(v0, v1);
      #pragma unroll
      for (int d = 1; d < 16; d <<= 1) m = fmaxf(m, __shfl_xor(m, d, 64));
      float s = __expf(v0 - m) + __expf(v1 - m);
      #pragma unroll
      for (int d = 1; d < 16; d <<= 1) s += __shfl_xor(s, d, 64);
      if ((lane & 15) == 0) {
        int row = wm * 64 + mt * 16 + (lane >> 4) * 4 + rg;
        pmax[(size_t)row * NPB + pb] = m;
        psum[(size_t)row * NPB + pb] = s;
      }
    }
  }
}

// ---------------- kernel 4: parallel LSE combine (one block per row) --------
__global__ __launch_bounds__(512) void combine_kernel(
    const float* __restrict__ pmax, const float* __restrict__ psum,
    float* __restrict__ lse) {
  int row = blockIdx.x, t = threadIdx.x;
  float m = pmax[(size_t)row * NPB + t];
  float s = psum[(size_t)row * NPB + t];
  float mw = m;
  #pragma unroll
  for (int d = 1; d < 64; d <<= 1) mw = fmaxf(mw, __shfl_xor(mw, d, 64));
  __shared__ float redm[8], reds[8];
  if ((t & 63) == 0) redm[t >> 6] = mw;
  __syncthreads();
  float M = fmaxf(fmaxf(fmaxf(redm[0], redm[1]), fmaxf(redm[2], redm[3])),
                  fmaxf(fmaxf(redm[4], redm[5]), fmaxf(redm[6], redm[7])));
  float sv = s * __expf(m - M);
  #pragma unroll
  for (int d = 1; d < 64; d <<= 1) sv += __shfl_xor(sv, d, 64);
  if ((t & 63) == 0) reds[t >> 6] = sv;
  __syncthreads();
  if (t == 0) {
    float S = reds[0] + reds[1] + reds[2] + reds[3]
            + reds[4] + reds[5] + reds[6] + reds[7];
    lse[row] = M + logf(S);
  }
}

// ---------------- kernel 5: group logic -> loss -----------------------------
__global__ __launch_bounds__(256) void finish_kernel(
    const float* __restrict__ lse, const float* __restrict__ s_own,
    const int* __restrict__ targets, const int* __restrict__ cams,
    float* __restrict__ out) {
  int i = threadIdx.x;
  float mylse = lse[i];

  __shared__ float so[256]; __shared__ int tg[256], cmn[256];
  __shared__ float gfirst[256];
  so[i] = s_own[i]; tg[i] = targets[i]; cmn[i] = cams[i];
  __syncthreads();
  int ti = tg[i], ci = cmn[i]; float soi = so[i];
  float gmin = 1e30f;
  bool grp_first = true, psid_first = true;
  for (int j = 0; j < 256; ++j) {
    if (tg[j] == ti) {
      if (j < i) psid_first = false;
      if (cmn[j] == ci) {
        gmin = fminf(gmin, so[j]);
        if (j < i) grp_first = false;
      }
    }
  }
  bool ismin = (soi <= gmin);
  gfirst[i] = grp_first ? 1.f : 0.f;
  __syncthreads();
  float ngroups = 0.f; bool prior = false;
  for (int j = 0; j < 256; ++j) {
    if (tg[j] == ti) {
      ngroups += gfirst[j];
      if (j < i && cmn[j] == ci && so[j] <= gmin) prior = true; // is_min[j], same gmin per group
    }
  }
  float contrib = (ismin && !prior) ? (mylse - soi) / ngroups : 0.f;
  float pf = psid_first ? 1.f : 0.f;
  #pragma unroll
  for (int d = 1; d < 64; d <<= 1) {
    contrib += __shfl_xor(contrib, d, 64);
    pf += __shfl_xor(pf, d, 64);
  }
  __shared__ float rc[4], rp[4];
  if ((i & 63) == 0) { rc[i >> 6] = contrib; rp[i >> 6] = pf; }
  __syncthreads();
  if (i == 0) out[0] = (rc[0] + rc[1] + rc[2] + rc[3]) / (rp[0] + rp[1] + rp[2] + rp[3]);
}

extern "C" void kernel_launch(void* const* d_in, const int* in_sizes, int n_in,
                              void* d_out, int out_size, void* d_ws, size_t ws_size,
                              hipStream_t stream) {
  const float* inputs  = (const float*)d_in[0];
  const float* feats   = (const float*)d_in[1];
  const int*   targets = (const int*)d_in[2];
  const int*   cams    = (const int*)d_in[3];
  float* out = (float*)d_out;
  char* ws = (char*)d_ws;
  // ws layout (16B-aligned): inv_norm 1KB | s_own 1KB | lse 1KB | pad |
  //                          pmax 512KB | psum 512KB | x_bf16 1MB
  float* inv_norm = (float*)(ws);
  float* s_own    = (float*)(ws + 1024);
  float* lse      = (float*)(ws + 2048);
  float* pmax     = (float*)(ws + 4096);
  float* psum     = (float*)(ws + 4096 + 512 * 1024);
  unsigned short* xb = (unsigned short*)(ws + 4096 + 1024 * 1024);

  norm_kernel<<<Bn, 256, 0, stream>>>(inputs, xb, inv_norm);
  sown_kernel<<<Bn, 256, 0, stream>>>(inputs, feats, targets, inv_norm, s_own);
  gemm_kernel<<<Nn / BN, 512, 0, stream>>>(xb, feats, pmax, psum);
  combine_kernel<<<Bn, NPB, 0, stream>>>(pmax, psum, lse);
  finish_kernel<<<1, 256, 0, stream>>>(lse, s_own, targets, cams, out);
}

// Round 3
// 108.387 us; speedup vs baseline: 2.0571x; 1.1055x over previous
//
#include <hip/hip_runtime.h>

// B=256 samples, D=2048 dims, N=16384 bank rows. Dominant cost:
// sims = normalize(inputs) @ features^T / 0.05 -> per-row logsumexp.
// GEMM is HBM-bound on features (134 MB f32, read once ~= 21 us floor).

constexpr int Bn = 256;     // batch
constexpr int Dk = 2048;    // feature dim
constexpr int Nn = 16384;   // bank rows
constexpr int BM = 128;     // rows per block (M split x2)
constexpr int BN = 64;      // N-cols per block
constexpr int BK = 64;      // K-chunk
constexpr int NK = Dk / BK; // 32
constexpr int NPB = 512;    // partial chunks (Nn/BN * 2)
constexpr float TEMP_INV = 20.0f;

typedef float f32x4 __attribute__((ext_vector_type(4)));
typedef short s16x8 __attribute__((ext_vector_type(8)));
typedef unsigned int u32x4 __attribute__((ext_vector_type(4)));

__device__ inline unsigned short f2bf(float f) {
  union { float f; unsigned u; } v; v.f = f;
  unsigned r = v.u + 0x7FFFu + ((v.u >> 16) & 1u);   // RNE
  return (unsigned short)(r >> 16);
}

// ---------------- kernel 1: normalize inputs -> bf16 + inv_norm + exact s_own
__global__ __launch_bounds__(256) void norm_sown_kernel(
    const float* __restrict__ x, const float* __restrict__ feats,
    const int* __restrict__ targets, unsigned short* __restrict__ xb,
    float* __restrict__ s_own) {
  int row = blockIdx.x, t = threadIdx.x;
  const float* xr = x + (size_t)row * Dk;
  const float* fr = feats + (size_t)targets[row] * Dk;
  float4 a  = *(const float4*)(xr + t * 8);
  float4 b  = *(const float4*)(xr + t * 8 + 4);
  float4 fa = *(const float4*)(fr + t * 8);
  float4 fb = *(const float4*)(fr + t * 8 + 4);
  float ss = a.x*a.x + a.y*a.y + a.z*a.z + a.w*a.w
           + b.x*b.x + b.y*b.y + b.z*b.z + b.w*b.w;
  float dt = a.x*fa.x + a.y*fa.y + a.z*fa.z + a.w*fa.w
           + b.x*fb.x + b.y*fb.y + b.z*fb.z + b.w*fb.w;
  #pragma unroll
  for (int d = 1; d < 64; d <<= 1) {
    ss += __shfl_xor(ss, d, 64);
    dt += __shfl_xor(dt, d, 64);
  }
  __shared__ float rs[4], rd[4];
  if ((t & 63) == 0) { rs[t >> 6] = ss; rd[t >> 6] = dt; }
  __syncthreads();
  float inv = rsqrtf(rs[0] + rs[1] + rs[2] + rs[3]);
  union { unsigned short s[8]; uint4 v; } pk;
  pk.s[0] = f2bf(a.x*inv); pk.s[1] = f2bf(a.y*inv);
  pk.s[2] = f2bf(a.z*inv); pk.s[3] = f2bf(a.w*inv);
  pk.s[4] = f2bf(b.x*inv); pk.s[5] = f2bf(b.y*inv);
  pk.s[6] = f2bf(b.z*inv); pk.s[7] = f2bf(b.w*inv);
  *(uint4*)(xb + (size_t)row * Dk + t * 8) = pk.v;
  if (t == 0) s_own[row] = (rd[0] + rd[1] + rd[2] + rd[3]) * inv * TEMP_INV;
}

// ---------------- kernel 2: pipelined GEMM + per-row partial max/sumexp -----
// grid = 512 (mb = bid>>8 in [0,2), nb = bid&255). 512 threads, 8 waves:
// wm = w>>1 in [0,4) -> 32 rows each; wn = w&1 -> 32 cols each.
// Double-buffered LDS, raw s_barrier + counted vmcnt (no vmcnt(0) drain in
// the loop). A (bf16, L2-hot) staged 1 step ahead via global_load_lds with
// pre-swizzled source; B (f32 feats, HBM) loaded to regs 2 steps ahead,
// cvt->bf16 + swizzled ds_write 1 step ahead.
__global__ __launch_bounds__(512) void gemm_kernel(
    const unsigned short* __restrict__ xb, const float* __restrict__ feats,
    float* __restrict__ pmax, float* __restrict__ psum) {
  __shared__ unsigned char As[2 * BM * 128]; // 32KB (2 x 128 rows x 128B)
  __shared__ unsigned char Bs[2 * BN * 128]; // 16KB

  int tid = threadIdx.x;
  int w = tid >> 6, lane = tid & 63;
  int wm = w >> 1, wn = w & 1;
  int bid = blockIdx.x;
  int mb = bid >> 8, nb = bid & 255;
  int n0 = nb * BN;

  f32x4 acc[2][2];
  #pragma unroll
  for (int mt = 0; mt < 2; ++mt)
    #pragma unroll
    for (int nt = 0; nt < 2; ++nt)
      acc[mt][nt] = (f32x4){0.f, 0.f, 0.f, 0.f};

  // A staging: 2 x global_load_lds(16B)/thread; granule-pre-swizzled source,
  // linear LDS dest (HW adds lane*16).
  auto stage_A = [&](int kt, int buf) {
    int k0 = kt * BK;
    #pragma unroll
    for (int j = 0; j < 2; ++j) {
      int G = w * 64 + j * 512 + lane;
      int r = G >> 3, g = G & 7;
      const unsigned short* src =
          xb + (size_t)(mb * BM + r) * Dk + k0 + ((g ^ (r & 7)) << 3);
      __builtin_amdgcn_global_load_lds(
          (const __attribute__((address_space(1))) unsigned int*)src,
          (__attribute__((address_space(3))) unsigned int*)
              (As + buf * 16384 + (w * 64 + j * 512) * 16),
          16, 0, 0);
    }
  };

  // B reg-load geometry: thread -> feature row br, 8-float granule bg
  int br = tid >> 3, bg = tid & 7;
  const float* fbase = feats + (size_t)(n0 + br) * Dk + bg * 8;
  unsigned char* bdst0 = Bs + br * 128 + ((bg ^ (br & 7)) << 4);

  auto write_B = [&](int buf, float4 f0, float4 f1) {
    union { unsigned short s[8]; u32x4 v; } pk;
    pk.s[0] = f2bf(f0.x); pk.s[1] = f2bf(f0.y); pk.s[2] = f2bf(f0.z); pk.s[3] = f2bf(f0.w);
    pk.s[4] = f2bf(f1.x); pk.s[5] = f2bf(f1.y); pk.s[6] = f2bf(f1.z); pk.s[7] = f2bf(f1.w);
    *(u32x4*)(bdst0 + buf * 8192) = pk.v;
  };

  auto compute = [&](int buf) {
    const unsigned char* Ab = As + buf * 16384;
    const unsigned char* Bb = Bs + buf * 8192;
    #pragma unroll
    for (int ks = 0; ks < 2; ++ks) {
      int g = ks * 4 + (lane >> 4);
      s16x8 bfr[2], afr[2];
      #pragma unroll
      for (int nt = 0; nt < 2; ++nt) {
        int n = wn * 32 + nt * 16 + (lane & 15);
        bfr[nt] = *(const s16x8*)(Bb + n * 128 + ((g ^ (n & 7)) << 4));
      }
      #pragma unroll
      for (int mt = 0; mt < 2; ++mt) {
        int r = wm * 32 + mt * 16 + (lane & 15);
        afr[mt] = *(const s16x8*)(Ab + r * 128 + ((g ^ (r & 7)) << 4));
      }
      #pragma unroll
      for (int mt = 0; mt < 2; ++mt)
        #pragma unroll
        for (int nt = 0; nt < 2; ++nt)
          acc[mt][nt] = __builtin_amdgcn_mfma_f32_16x16x32_bf16(
              afr[mt], bfr[nt], acc[mt][nt], 0, 0, 0);
    }
  };

  // ---- prologue: tile 0 fully staged; B(1) regs in flight ----
  stage_A(0, 0);
  float4 f0 = *(const float4*)(fbase);
  float4 f1 = *(const float4*)(fbase + 4);
  write_B(0, f0, f1);              // compiler waits its own vmcnt for f0/f1
  f0 = *(const float4*)(fbase + BK);
  f1 = *(const float4*)(fbase + BK + 4);

  // ---- main loop: compute(t) while staging t+1, loading B(t+2) ----
  for (int t = 0; t < NK - 1; ++t) {
    int nbuf = (t + 1) & 1;
    stage_A(t + 1, nbuf);
    write_B(nbuf, f0, f1);         // B(t+1); compiler-counted vmcnt for regs
    int tn = (t + 2 < NK) ? (t + 2) : (NK - 1);   // clamped tail reload
    f0 = *(const float4*)(fbase + tn * BK);
    f1 = *(const float4*)(fbase + tn * BK + 4);
    asm volatile("s_waitcnt vmcnt(4)" ::: "memory");  // A(t)+B(t+1) landed; A(t+1),B(t+2) in flight
    asm volatile("s_waitcnt lgkmcnt(0)" ::: "memory"); // ds_writes visible
    __builtin_amdgcn_s_barrier();
    __builtin_amdgcn_sched_barrier(0);
    compute(t & 1);
    __builtin_amdgcn_sched_barrier(0);
    __builtin_amdgcn_s_barrier();  // protect buf (t&1) before overwrite at t+1
  }
  // ---- peeled last tile: full drain ----
  asm volatile("s_waitcnt vmcnt(0)" ::: "memory");
  asm volatile("s_waitcnt lgkmcnt(0)" ::: "memory");
  __builtin_amdgcn_s_barrier();
  __builtin_amdgcn_sched_barrier(0);
  compute((NK - 1) & 1);

  // epilogue: per-row partial max / sumexp over this wave's 32 cols.
  // C/D layout: col = lane&15, row = (lane>>4)*4 + reg
  int pb = nb * 2 + wn;
  #pragma unroll
  for (int mt = 0; mt < 2; ++mt) {
    #pragma unroll
    for (int rg = 0; rg < 4; ++rg) {
      float v0 = acc[mt][0][rg] * TEMP_INV;
      float v1 = acc[mt][1][rg] * TEMP_INV;
      float m = fmaxf(v0, v1);
      #pragma unroll
      for (int d = 1; d < 16; d <<= 1) m = fmaxf(m, __shfl_xor(m, d, 64));
      float s = __expf(v0 - m) + __expf(v1 - m);
      #pragma unroll
      for (int d = 1; d < 16; d <<= 1) s += __shfl_xor(s, d, 64);
      if ((lane & 15) == 0) {
        int row = mb * BM + wm * 32 + mt * 16 + (lane >> 4) * 4 + rg;
        pmax[(size_t)row * NPB + pb] = m;
        psum[(size_t)row * NPB + pb] = s;
      }
    }
  }
}

// ---------------- kernel 3: parallel LSE combine (one block per row) --------
__global__ __launch_bounds__(512) void combine_kernel(
    const float* __restrict__ pmax, const float* __restrict__ psum,
    float* __restrict__ lse) {
  int row = blockIdx.x, t = threadIdx.x;
  float m = pmax[(size_t)row * NPB + t];
  float s = psum[(size_t)row * NPB + t];
  float mw = m;
  #pragma unroll
  for (int d = 1; d < 64; d <<= 1) mw = fmaxf(mw, __shfl_xor(mw, d, 64));
  __shared__ float redm[8], reds[8];
  if ((t & 63) == 0) redm[t >> 6] = mw;
  __syncthreads();
  float M = fmaxf(fmaxf(fmaxf(redm[0], redm[1]), fmaxf(redm[2], redm[3])),
                  fmaxf(fmaxf(redm[4], redm[5]), fmaxf(redm[6], redm[7])));
  float sv = s * __expf(m - M);
  #pragma unroll
  for (int d = 1; d < 64; d <<= 1) sv += __shfl_xor(sv, d, 64);
  if ((t & 63) == 0) reds[t >> 6] = sv;
  __syncthreads();
  if (t == 0) {
    float S = reds[0] + reds[1] + reds[2] + reds[3]
            + reds[4] + reds[5] + reds[6] + reds[7];
    lse[row] = M + logf(S);
  }
}

// ---------------- kernel 4: group logic -> loss -----------------------------
__global__ __launch_bounds__(256) void finish_kernel(
    const float* __restrict__ lse, const float* __restrict__ s_own,
    const int* __restrict__ targets, const int* __restrict__ cams,
    float* __restrict__ out) {
  int i = threadIdx.x;
  float mylse = lse[i];

  __shared__ float so[256]; __shared__ int tg[256], cmn[256];
  __shared__ float gfirst[256];
  so[i] = s_own[i]; tg[i] = targets[i]; cmn[i] = cams[i];
  __syncthreads();
  int ti = tg[i], ci = cmn[i]; float soi = so[i];
  float gmin = 1e30f;
  bool grp_first = true, psid_first = true;
  for (int j = 0; j < 256; ++j) {
    if (tg[j] == ti) {
      if (j < i) psid_first = false;
      if (cmn[j] == ci) {
        gmin = fminf(gmin, so[j]);
        if (j < i) grp_first = false;
      }
    }
  }
  bool ismin = (soi <= gmin);
  gfirst[i] = grp_first ? 1.f : 0.f;
  __syncthreads();
  float ngroups = 0.f; bool prior = false;
  for (int j = 0; j < 256; ++j) {
    if (tg[j] == ti) {
      ngroups += gfirst[j];
      if (j < i && cmn[j] == ci && so[j] <= gmin) prior = true;
    }
  }
  float contrib = (ismin && !prior) ? (mylse - soi) / ngroups : 0.f;
  float pf = psid_first ? 1.f : 0.f;
  #pragma unroll
  for (int d = 1; d < 64; d <<= 1) {
    contrib += __shfl_xor(contrib, d, 64);
    pf += __shfl_xor(pf, d, 64);
  }
  __shared__ float rc[4], rp[4];
  if ((i & 63) == 0) { rc[i >> 6] = contrib; rp[i >> 6] = pf; }
  __syncthreads();
  if (i == 0) out[0] = (rc[0] + rc[1] + rc[2] + rc[3]) / (rp[0] + rp[1] + rp[2] + rp[3]);
}

extern "C" void kernel_launch(void* const* d_in, const int* in_sizes, int n_in,
                              void* d_out, int out_size, void* d_ws, size_t ws_size,
                              hipStream_t stream) {
  const float* inputs  = (const float*)d_in[0];
  const float* feats   = (const float*)d_in[1];
  const int*   targets = (const int*)d_in[2];
  const int*   cams    = (const int*)d_in[3];
  float* out = (float*)d_out;
  char* ws = (char*)d_ws;
  // ws: inv/s_own/lse 3KB | pad | pmax 512KB | psum 512KB | x_bf16 1MB
  float* s_own    = (float*)(ws + 1024);
  float* lse      = (float*)(ws + 2048);
  float* pmax     = (float*)(ws + 4096);
  float* psum     = (float*)(ws + 4096 + 512 * 1024);
  unsigned short* xb = (unsigned short*)(ws + 4096 + 1024 * 1024);

  norm_sown_kernel<<<Bn, 256, 0, stream>>>(inputs, feats, targets, xb, s_own);
  gemm_kernel<<<(Bn / BM) * (Nn / BN), 512, 0, stream>>>(xb, feats, pmax, psum);
  combine_kernel<<<Bn, NPB, 0, stream>>>(pmax, psum, lse);
  finish_kernel<<<1, 256, 0, stream>>>(lse, s_own, targets, cams, out);
}